// Round 1
// baseline (122.471 us; speedup 1.0000x reference)
//
#include <hip/hip_runtime.h>

// Problem: A=8, B=16, N=M=1024, K=64. u:(A,B,N,K) f32, v:(A,B,M,K) f32.
// out0 = u * (row_sum > 0), out1 = v * (col_sum > 0)
// row_sum[n] = dot(u[n,:], v_sum), col_sum[m] = dot(v[m,:], u_sum)

#define NBATCH 128        // A*B
#define NROW   1024       // N == M
#define KDIM   64
#define ELEMS_PER_TENSOR (128ull * 1024ull * 64ull)  // 8388608

// ---------------- Kernel 1: per-batch column sums of u and v ----------------
// grid: 512 blocks (4 per batch) x 256 threads. float4 loads.
// sums layout in ws: [0 .. 8191]   = v_sum per batch (masks u)
//                    [8192..16383] = u_sum per batch (masks v)
__global__ void sums_kernel(const float* __restrict__ u,
                            const float* __restrict__ v,
                            float* __restrict__ sums) {
    int bid   = blockIdx.x;
    int batch = bid >> 2;             // 0..127
    int rstart = (bid & 3) * 256;     // this block covers 256 rows
    int tid = threadIdx.x;            // 0..255
    int k4  = tid & 15;               // which float4 column group (k = 4*k4..+3)
    int rg  = tid >> 4;               // 0..15 row group

    const float4* ub = (const float4*)(u + ((size_t)batch * NROW + rstart) * KDIM);
    const float4* vb = (const float4*)(v + ((size_t)batch * NROW + rstart) * KDIM);

    float4 su = make_float4(0.f, 0.f, 0.f, 0.f);
    float4 sv = make_float4(0.f, 0.f, 0.f, 0.f);
    #pragma unroll 4
    for (int i = 0; i < 16; ++i) {
        int r = rg + 16 * i;          // 0..255
        float4 a = ub[r * 16 + k4];   // wave: 4 consecutive rows x 256B, coalesced
        float4 b = vb[r * 16 + k4];
        su.x += a.x; su.y += a.y; su.z += a.z; su.w += a.w;
        sv.x += b.x; sv.y += b.y; sv.z += b.z; sv.w += b.w;
    }

    __shared__ float4 lu[16][16];
    __shared__ float4 lv[16][16];
    lu[rg][k4] = su;
    lv[rg][k4] = sv;
    __syncthreads();

    if (tid < 16) {
        float4 tu = make_float4(0.f, 0.f, 0.f, 0.f);
        float4 tv = make_float4(0.f, 0.f, 0.f, 0.f);
        #pragma unroll
        for (int i = 0; i < 16; ++i) {
            float4 a = lu[i][tid];
            float4 b = lv[i][tid];
            tu.x += a.x; tu.y += a.y; tu.z += a.z; tu.w += a.w;
            tv.x += b.x; tv.y += b.y; tv.z += b.z; tv.w += b.w;
        }
        // v_sum -> region 0 (used to mask u); u_sum -> region 1 (masks v)
        float* dv = sums + batch * KDIM + tid * 4;
        float* du = sums + NBATCH * KDIM + batch * KDIM + tid * 4;
        atomicAdd(dv + 0, tv.x); atomicAdd(dv + 1, tv.y);
        atomicAdd(dv + 2, tv.z); atomicAdd(dv + 3, tv.w);
        atomicAdd(du + 0, tu.x); atomicAdd(du + 1, tu.y);
        atomicAdd(du + 2, tu.z); atomicAdd(du + 3, tu.w);
    }
}

// ---------------- Kernel 2: row dot + predicated copy ----------------
// grid: 16384 blocks x 256 threads. First 8192 blocks handle u, rest handle v.
// Each 16-lane subgroup owns one row (64 floats = 16 lanes x float4).
__global__ void mask_kernel(const float* __restrict__ u,
                            const float* __restrict__ v,
                            const float* __restrict__ sums,
                            float* __restrict__ out) {
    int bid  = blockIdx.x;
    int is_v = bid >> 13;             // 0 for u, 1 for v
    int lb   = bid & 8191;            // 64 blocks per batch
    const float* src = is_v ? v : u;
    const float* s   = sums + is_v * (NBATCH * KDIM);
    float* dst = out + (size_t)is_v * ELEMS_PER_TENSOR;

    int batch = lb >> 6;              // 0..127
    int row0  = (lb & 63) * 16;       // 16 rows per block
    int tid = threadIdx.x;
    int k4  = tid & 15;
    int r   = row0 + (tid >> 4);

    size_t off = ((size_t)batch * NROW + r) * KDIM + (size_t)k4 * 4;
    float4 x  = *(const float4*)(src + off);
    float4 sv = *(const float4*)(s + batch * KDIM + k4 * 4);

    float p = x.x * sv.x + x.y * sv.y + x.z * sv.z + x.w * sv.w;
    // reduce across the 16 lanes that share a row (xor masks stay in-group)
    p += __shfl_xor(p, 1);
    p += __shfl_xor(p, 2);
    p += __shfl_xor(p, 4);
    p += __shfl_xor(p, 8);

    float m = (p > 0.f) ? 1.f : 0.f;
    float4 o = make_float4(x.x * m, x.y * m, x.z * m, x.w * m);
    *(float4*)(dst + off) = o;
}

extern "C" void kernel_launch(void* const* d_in, const int* in_sizes, int n_in,
                              void* d_out, int out_size, void* d_ws, size_t ws_size,
                              hipStream_t stream) {
    const float* u = (const float*)d_in[0];
    const float* v = (const float*)d_in[1];
    float* out  = (float*)d_out;
    float* sums = (float*)d_ws;      // 2 * 128 * 64 floats = 64 KB

    hipMemsetAsync(d_ws, 0, 2 * NBATCH * KDIM * sizeof(float), stream);
    sums_kernel<<<dim3(512), dim3(256), 0, stream>>>(u, v, sums);
    mask_kernel<<<dim3(16384), dim3(256), 0, stream>>>(u, v, sums, out);
}

// Round 2
// 120.511 us; speedup vs baseline: 1.0163x; 1.0163x over previous
//
#include <hip/hip_runtime.h>

// Problem: A=8, B=16, N=M=1024, K=64. u:(A,B,N,K) f32, v:(A,B,M,K) f32.
// out0 = u * (dot(u_row, v_sum) > 0), out1 = v * (dot(v_row, u_sum) > 0)
//
// ws layout: float ws[128][4][2][64]
//   [batch][part][0][k] = partial column-sum of v (masks u)
//   [batch][part][1][k] = partial column-sum of u (masks v)
// No memset needed: sums_kernel fully overwrites all 256 KB.

#define NBATCH 128        // A*B
#define NROW   1024       // N == M
#define KDIM   64
#define NPART  4
#define ELEMS_PER_TENSOR (128ull * 1024ull * 64ull)  // 8388608

// ---------------- Kernel 1: per-batch partial column sums of u and v --------
// grid: 512 blocks (4 per batch) x 256 threads. float4 loads, no atomics.
__global__ void sums_kernel(const float* __restrict__ u,
                            const float* __restrict__ v,
                            float* __restrict__ sums) {
    int bid    = blockIdx.x;
    int batch  = bid >> 2;            // 0..127
    int part   = bid & 3;
    int rstart = part * 256;          // this block covers 256 rows
    int tid = threadIdx.x;            // 0..255
    int k4  = tid & 15;               // float4 column group
    int rg  = tid >> 4;               // 0..15 row group

    const float4* ub = (const float4*)(u + ((size_t)batch * NROW + rstart) * KDIM);
    const float4* vb = (const float4*)(v + ((size_t)batch * NROW + rstart) * KDIM);

    float4 su = make_float4(0.f, 0.f, 0.f, 0.f);
    float4 sv = make_float4(0.f, 0.f, 0.f, 0.f);
    #pragma unroll 4
    for (int i = 0; i < 16; ++i) {
        int r = rg + 16 * i;          // 0..255
        float4 a = ub[r * 16 + k4];   // wave covers 4 rows x 256B contiguous
        float4 b = vb[r * 16 + k4];
        su.x += a.x; su.y += a.y; su.z += a.z; su.w += a.w;
        sv.x += b.x; sv.y += b.y; sv.z += b.z; sv.w += b.w;
    }

    __shared__ float4 lu[16][16];
    __shared__ float4 lv[16][16];
    lu[rg][k4] = su;
    lv[rg][k4] = sv;
    __syncthreads();

    if (tid < 32) {
        int which = tid >> 4;         // 0 -> v partial, 1 -> u partial
        int c     = tid & 15;
        float4 t = make_float4(0.f, 0.f, 0.f, 0.f);
        if (which == 0) {
            #pragma unroll
            for (int i = 0; i < 16; ++i) {
                float4 b = lv[i][c];
                t.x += b.x; t.y += b.y; t.z += b.z; t.w += b.w;
            }
        } else {
            #pragma unroll
            for (int i = 0; i < 16; ++i) {
                float4 a = lu[i][c];
                t.x += a.x; t.y += a.y; t.z += a.z; t.w += a.w;
            }
        }
        float* dst = sums + (((size_t)(batch * NPART + part) * 2 + which) * KDIM) + c * 4;
        *(float4*)dst = t;
    }
}

// ---------------- Kernel 2: fold partials + row dot + predicated copy ------
// grid: 16384 blocks x 256 threads. Blocks [0,8192) handle u, rest handle v.
// Each 16-lane subgroup owns one row (64 floats = 16 lanes x float4).
__global__ void mask_kernel(const float* __restrict__ u,
                            const float* __restrict__ v,
                            const float* __restrict__ sums,
                            float* __restrict__ out) {
    int bid  = blockIdx.x;
    int is_v = bid >> 13;             // 0 for u, 1 for v
    int lb   = bid & 8191;            // 64 blocks per batch
    const float* src = is_v ? v : u;
    float* dst = out + (size_t)is_v * ELEMS_PER_TENSOR;

    int batch = lb >> 6;              // 0..127
    int row0  = (lb & 63) * 16;       // 16 rows per block
    int tid   = threadIdx.x;

    // Fold the 4 partials of the sum we need (which == is_v) into LDS once.
    __shared__ float s_lds[KDIM];
    if (tid < KDIM) {
        const float* p0 = sums + ((size_t)(batch * NPART) * 2 + is_v) * KDIM + tid;
        s_lds[tid] = p0[0] + p0[2 * KDIM] + p0[4 * KDIM] + p0[6 * KDIM];
    }
    __syncthreads();

    int k4 = tid & 15;
    int r  = row0 + (tid >> 4);

    size_t off = ((size_t)batch * NROW + r) * KDIM + (size_t)k4 * 4;
    float4 x   = *(const float4*)(src + off);
    float4 sv4 = *(const float4*)(s_lds + k4 * 4);   // 2-way bank alias: free

    float p = x.x * sv4.x + x.y * sv4.y + x.z * sv4.z + x.w * sv4.w;
    // reduce across the 16 lanes sharing a row (xor masks stay in-group)
    p += __shfl_xor(p, 1);
    p += __shfl_xor(p, 2);
    p += __shfl_xor(p, 4);
    p += __shfl_xor(p, 8);

    float m = (p > 0.f) ? 1.f : 0.f;
    float4 o = make_float4(x.x * m, x.y * m, x.z * m, x.w * m);
    *(float4*)(dst + off) = o;
}

extern "C" void kernel_launch(void* const* d_in, const int* in_sizes, int n_in,
                              void* d_out, int out_size, void* d_ws, size_t ws_size,
                              hipStream_t stream) {
    const float* u = (const float*)d_in[0];
    const float* v = (const float*)d_in[1];
    float* out  = (float*)d_out;
    float* sums = (float*)d_ws;      // 128*4*2*64 floats = 256 KB, fully overwritten

    sums_kernel<<<dim3(512), dim3(256), 0, stream>>>(u, v, sums);
    mask_kernel<<<dim3(16384), dim3(256), 0, stream>>>(u, v, sums, out);
}